// Round 1
// baseline (5357.649 us; speedup 1.0000x reference)
//
#include <hip/hip_runtime.h>
#include <math.h>

// Problem constants: E=8, TOP=2, C=128, H=96, W=96, B=8, NUM_GATES=4, KH=3
#define CHW 9216          // 96*96
#define OUT_PER_GATE 9437184  // 8*128*96*96

// ws layout (floats):
// [0,1024)    x_gap[8][128]
// [1024,1280) Wgt[4][8][8]   (gate g, batch b, expert e) -> mix weight
// [1280,1344) needed[8][8]   (expert e, batch b) as int

// ---------------------------------------------------------------- x_gap
__global__ void gap_kernel(const float* __restrict__ x, float* __restrict__ xgap) {
    int bc = blockIdx.x;                       // b*128 + c
    const float* p = x + (size_t)bc * CHW;
    float s = 0.f;
    for (int i = threadIdx.x; i < CHW; i += 256) s += p[i];
    __shared__ float red[256];
    red[threadIdx.x] = s;
    __syncthreads();
    for (int off = 128; off > 0; off >>= 1) {
        if (threadIdx.x < off) red[threadIdx.x] += red[threadIdx.x + off];
        __syncthreads();
    }
    if (threadIdx.x == 0) xgap[bc] = red[0] * (1.0f / 9216.0f);
}

// ---------------------------------------------------------------- gating
// 1 block, 64 threads: thread t -> (b = t>>3, e = t&7). Exact fp32.
__global__ void gate_kernel(const float* __restrict__ G, float* __restrict__ ws,
                            float* __restrict__ loss_out) {
    __shared__ float gap_s[1024];
    __shared__ float logits[64];
    __shared__ float probs[64];
    __shared__ float vsum[8];
    __shared__ float losses[4];
    int t = threadIdx.x;
    for (int i = t; i < 1024; i += 64) gap_s[i] = ws[i];
    int b = t >> 3, e = t & 7;
    float* Wgt = ws + 1024;
    int* needed = (int*)(ws + 1280);
    needed[t] = 0;
    __syncthreads();
    for (int g = 0; g < 4; ++g) {
        float acc = 0.f;
        const float* Gg = G + g * 1024;        // G[g][c][e], c-major stride 8
        for (int c = 0; c < 128; ++c) acc += gap_s[b * 128 + c] * Gg[c * 8 + e];
        logits[t] = acc;
        __syncthreads();
        float m = -1e30f;
        for (int j = 0; j < 8; ++j) m = fmaxf(m, logits[b * 8 + j]);
        float den = 0.f;
        for (int j = 0; j < 8; ++j) den += expf(logits[b * 8 + j] - m);
        float pr = expf(acc - m) / den;
        probs[t] = pr;
        __syncthreads();
        if (e == 0) {
            // top-2, first index wins ties (matches jax.lax.top_k)
            int i0 = 0; float v0 = probs[b * 8];
            for (int j = 1; j < 8; ++j) { float v = probs[b * 8 + j]; if (v > v0) { v0 = v; i0 = j; } }
            int i1 = -1; float v1 = -1e30f;
            for (int j = 0; j < 8; ++j) { if (j == i0) continue; float v = probs[b * 8 + j]; if (v > v1) { v1 = v; i1 = j; } }
            float r = expf(v1 - v0);           // softmax over [v0, v1], v0 is max
            float inv = 1.f / (1.f + r);
            for (int j = 0; j < 8; ++j) Wgt[g * 64 + b * 8 + j] = 0.f;
            Wgt[g * 64 + b * 8 + i0] = inv;
            Wgt[g * 64 + b * 8 + i1] = r * inv;
            needed[i0 * 8 + b] = 1;
            needed[i1 * 8 + b] = 1;
        }
        if (t < 8) {                           // t == e index for column sums
            float v = 0.f;
            for (int bb = 0; bb < 8; ++bb) v += probs[bb * 8 + t];
            vsum[t] = v;
        }
        __syncthreads();
        if (t == 0) {
            float mean = 0.f;
            for (int j = 0; j < 8; ++j) mean += vsum[j];
            mean *= 0.125f;
            float var = 0.f;
            for (int j = 0; j < 8; ++j) { float d = vsum[j] - mean; var += d * d; }
            var *= (1.f / 7.f);                // ddof=1
            losses[g] = var / (mean * mean + 1e-10f);
        }
        __syncthreads();
    }
    if (t == 0) loss_out[0] = 0.25f * (losses[0] + losses[1] + losses[2] + losses[3]);
}

// ---------------------------------------------------------------- fused expert
// Block: one (e, b, row h). 256 threads: q = t&31 -> pixels {q, q+32, q+64},
// g8 = t>>5 -> output channels [g8*16, g8*16+16). conv -> relu -> squash ->
// pointwise -> gate-weighted atomicAdd into up to 4 outputs.
__launch_bounds__(256)
__global__ void expert_kernel(const float* __restrict__ x,
                              const float* __restrict__ Wc,
                              const float* __restrict__ bc,
                              const float* __restrict__ Wp,
                              const float* __restrict__ bp,
                              const float* __restrict__ ws,
                              float* __restrict__ out) {
    int h = blockIdx.x, b = blockIdx.y, e = blockIdx.z;
    const int* needed = (const int*)(ws + 1280);
    if (needed[e * 8 + b] == 0) return;

    float gw[4];
    #pragma unroll
    for (int g = 0; g < 4; ++g) gw[g] = ws[1024 + g * 64 + b * 8 + e];

    // LDS union (60416 B):
    // phase1: in_s[8][3][98] @0 (2352f), w_s[128][72] @2352 (9216f)
    // phase2: us_s[128][96] @0 (12288f), part_s[8][96] @12288 (768f),
    //         wp_s[128][16] @13056 (2048f)
    __shared__ float smem[15104];
    float* in_s   = smem;
    float* w_s    = smem + 2352;
    float* us_s   = smem;
    float* part_s = smem + 12288;
    float* wp_s   = smem + 13056;

    int t = threadIdx.x;
    int q = t & 31;
    int g8 = t >> 5;
    int obase = g8 * 16;

    float acc[16][3];
    #pragma unroll
    for (int j = 0; j < 16; ++j) { acc[j][0] = 0.f; acc[j][1] = 0.f; acc[j][2] = 0.f; }

    const float* xb  = x + (size_t)b * 128 * CHW;
    const float* wce = Wc + (size_t)e * 147456;   // 128*128*9

    for (int cc = 0; cc < 16; ++cc) {             // in-channel chunks of 8
        __syncthreads();
        // stage input: 8 ch x 3 rows x 98 cols (img col = lds col - 1)
        for (int idx = t; idx < 2352; idx += 256) {
            int ci  = idx / 294;                  // 3*98
            int rem = idx - ci * 294;
            int r   = rem / 98;
            int col = rem - r * 98 - 1;
            int row = h - 1 + r;
            float v = 0.f;
            if (row >= 0 && row < 96 && col >= 0 && col < 96)
                v = xb[(cc * 8 + ci) * CHW + row * 96 + col];
            in_s[idx] = v;
        }
        // stage weights w_s[o][k], k = ci_local*9 + ky*3 + kx (72 per o)
        for (int idx = t; idx < 9216; idx += 256) {
            int o = idx / 72;
            w_s[idx] = wce[o * 1080 + cc * 72 + idx];   // = o*1152 + cc*72 + k
        }
        __syncthreads();

        for (int ci = 0; ci < 8; ++ci) {
            const float* ibase = in_s + ci * 294;
            float iv[3][3][3];                    // [ky][pix][kx]
            #pragma unroll
            for (int ky = 0; ky < 3; ++ky)
                #pragma unroll
                for (int i = 0; i < 3; ++i)
                    #pragma unroll
                    for (int kx = 0; kx < 3; ++kx)
                        iv[ky][i][kx] = ibase[ky * 98 + q + 32 * i + kx];
            #pragma unroll
            for (int j = 0; j < 16; ++j) {
                const float* wb = w_s + (obase + j) * 72 + ci * 9;
                #pragma unroll
                for (int ky = 0; ky < 3; ++ky) {
                    #pragma unroll
                    for (int kx = 0; kx < 3; ++kx) {
                        float wv = wb[ky * 3 + kx];   // lane-broadcast LDS read
                        acc[j][0] += wv * iv[ky][0][kx];
                        acc[j][1] += wv * iv[ky][1][kx];
                        acc[j][2] += wv * iv[ky][2][kx];
                    }
                }
            }
        }
    }

    // bias + relu
    #pragma unroll
    for (int j = 0; j < 16; ++j) {
        float bias = bc[e * 128 + obase + j];
        acc[j][0] = fmaxf(acc[j][0] + bias, 0.f);
        acc[j][1] = fmaxf(acc[j][1] + bias, 0.f);
        acc[j][2] = fmaxf(acc[j][2] + bias, 0.f);
    }

    // squash: sn per pixel over all 128 channels (8 partial groups)
    float sp0 = 0.f, sp1 = 0.f, sp2 = 0.f;
    #pragma unroll
    for (int j = 0; j < 16; ++j) {
        sp0 += acc[j][0] * acc[j][0];
        sp1 += acc[j][1] * acc[j][1];
        sp2 += acc[j][2] * acc[j][2];
    }
    part_s[g8 * 96 + q]      = sp0;
    part_s[g8 * 96 + q + 32] = sp1;
    part_s[g8 * 96 + q + 64] = sp2;
    __syncthreads();   // conv LDS reads done; part_s visible
    float fs[3];
    #pragma unroll
    for (int i = 0; i < 3; ++i) {
        float sn = 0.f;
        #pragma unroll
        for (int g = 0; g < 8; ++g) sn += part_s[g * 96 + q + 32 * i];
        fs[i] = sn / ((1.f + sn) * sqrtf(sn + 1e-8f));
    }
    #pragma unroll
    for (int j = 0; j < 16; ++j) {
        us_s[(obase + j) * 96 + q]      = acc[j][0] * fs[0];
        us_s[(obase + j) * 96 + q + 32] = acc[j][1] * fs[1];
        us_s[(obase + j) * 96 + q + 64] = acc[j][2] * fs[2];
    }

    // pointwise: y[o] = sum_c Wp[e][o][c] * us[c] + bp  (K=128 in chunks of 16)
    #pragma unroll
    for (int j = 0; j < 16; ++j) { acc[j][0] = 0.f; acc[j][1] = 0.f; acc[j][2] = 0.f; }
    const float* wpe = Wp + (size_t)e * 16384;
    for (int wcch = 0; wcch < 8; ++wcch) {
        __syncthreads();
        for (int idx = t; idx < 2048; idx += 256) {
            int o = idx >> 4, cl = idx & 15;
            wp_s[idx] = wpe[o * 128 + wcch * 16 + cl];
        }
        __syncthreads();
        for (int cl = 0; cl < 16; ++cl) {
            int c = wcch * 16 + cl;
            float u0 = us_s[c * 96 + q];
            float u1 = us_s[c * 96 + q + 32];
            float u2 = us_s[c * 96 + q + 64];
            #pragma unroll
            for (int j = 0; j < 16; ++j) {
                float wv = wp_s[(obase + j) * 16 + cl];
                acc[j][0] += wv * u0;
                acc[j][1] += wv * u1;
                acc[j][2] += wv * u2;
            }
        }
    }
    #pragma unroll
    for (int j = 0; j < 16; ++j) {
        float bias = bp[e * 128 + obase + j];
        acc[j][0] += bias; acc[j][1] += bias; acc[j][2] += bias;
    }

    // gate-weighted scatter
    #pragma unroll
    for (int g = 0; g < 4; ++g) {
        float wv = gw[g];
        if (wv != 0.f) {
            float* og = out + (size_t)g * OUT_PER_GATE + (size_t)(b * 128) * CHW + h * 96;
            #pragma unroll
            for (int j = 0; j < 16; ++j) {
                float* oc = og + (size_t)(obase + j) * CHW;
                atomicAdd(oc + q,      wv * acc[j][0]);
                atomicAdd(oc + q + 32, wv * acc[j][1]);
                atomicAdd(oc + q + 64, wv * acc[j][2]);
            }
        }
    }
}

// ---------------------------------------------------------------- launch
extern "C" void kernel_launch(void* const* d_in, const int* in_sizes, int n_in,
                              void* d_out, int out_size, void* d_ws, size_t ws_size,
                              hipStream_t stream) {
    const float* x  = (const float*)d_in[0];
    const float* G  = (const float*)d_in[1];
    const float* Wc = (const float*)d_in[2];
    const float* bc = (const float*)d_in[3];
    const float* Wp = (const float*)d_in[4];
    const float* bp = (const float*)d_in[5];
    float* out = (float*)d_out;
    float* ws  = (float*)d_ws;

    hipMemsetAsync(d_out, 0, (size_t)out_size * sizeof(float), stream);
    gap_kernel<<<dim3(1024), dim3(256), 0, stream>>>(x, ws);
    gate_kernel<<<dim3(1), dim3(64), 0, stream>>>(G, ws, out + (size_t)4 * OUT_PER_GATE);
    expert_kernel<<<dim3(96, 8, 8), dim3(256), 0, stream>>>(x, Wc, bc, Wp, bp, ws, out);
}

// Round 3
// 604.519 us; speedup vs baseline: 8.8627x; 8.8627x over previous
//
#include <hip/hip_runtime.h>
#include <math.h>

// E=8, TOP=2, C=128, H=96, W=96, B=8, NUM_GATES=4, KH=3
#define CHW 9216
#define OPG 9437184  // 8*128*96*96

typedef unsigned short u16;
typedef __attribute__((ext_vector_type(8))) short short8;   // 8 x bf16 (4 VGPR)
typedef __attribute__((ext_vector_type(4))) float f32x4;

// ws layout (bytes):
// [0, 8192)            gating area (floats): x_gap[1024], Wgt[4][8][8]@1024f, needed[64]@1280f
// [8192, 18882560)     X_t  bf16 [b][hf][h][w][c64]  (c swizzled: c^( (w&7)<<3 ))
// [18882560, 21241856) A_t  bf16 [e][hf][r][o][c64]  (plain)
// [21241856, 21504000) Wp_t bf16 [e][o][c128]        (plain)
#define WS_XT  8192
#define WS_AT  18882560
#define WS_WPT 21241856

__device__ __forceinline__ u16 f2bf(float f) {
    unsigned u = __float_as_uint(f);
    u += 0x7fff + ((u >> 16) & 1);      // RNE
    return (u16)(u >> 16);
}

// ---------------------------------------------------------------- x_gap
__global__ void gap_kernel(const float* __restrict__ x, float* __restrict__ xgap) {
    int bc = blockIdx.x;
    const float* p = x + (size_t)bc * CHW;
    float s = 0.f;
    for (int i = threadIdx.x; i < CHW; i += 256) s += p[i];
    __shared__ float red[256];
    red[threadIdx.x] = s;
    __syncthreads();
    for (int off = 128; off > 0; off >>= 1) {
        if (threadIdx.x < off) red[threadIdx.x] += red[threadIdx.x + off];
        __syncthreads();
    }
    if (threadIdx.x == 0) xgap[bc] = red[0] * (1.0f / 9216.0f);
}

// ---------------------------------------------------------------- gating (exact fp32)
__global__ void gate_kernel(const float* __restrict__ G, float* __restrict__ ws,
                            float* __restrict__ loss_out) {
    __shared__ float gap_s[1024];
    __shared__ float logits[64];
    __shared__ float probs[64];
    __shared__ float vsum[8];
    __shared__ float losses[4];
    int t = threadIdx.x;
    for (int i = t; i < 1024; i += 64) gap_s[i] = ws[i];
    int b = t >> 3, e = t & 7;
    float* Wgt = ws + 1024;
    int* needed = (int*)(ws + 1280);
    needed[t] = 0;
    __syncthreads();
    for (int g = 0; g < 4; ++g) {
        float acc = 0.f;
        const float* Gg = G + g * 1024;
        for (int c = 0; c < 128; ++c) acc += gap_s[b * 128 + c] * Gg[c * 8 + e];
        logits[t] = acc;
        __syncthreads();
        float m = -1e30f;
        for (int j = 0; j < 8; ++j) m = fmaxf(m, logits[b * 8 + j]);
        float den = 0.f;
        for (int j = 0; j < 8; ++j) den += expf(logits[b * 8 + j] - m);
        float pr = expf(acc - m) / den;
        probs[t] = pr;
        __syncthreads();
        if (e == 0) {
            int i0 = 0; float v0 = probs[b * 8];
            for (int j = 1; j < 8; ++j) { float v = probs[b * 8 + j]; if (v > v0) { v0 = v; i0 = j; } }
            int i1 = -1; float v1 = -1e30f;
            for (int j = 0; j < 8; ++j) { if (j == i0) continue; float v = probs[b * 8 + j]; if (v > v1) { v1 = v; i1 = j; } }
            float r = expf(v1 - v0);
            float inv = 1.f / (1.f + r);
            for (int j = 0; j < 8; ++j) Wgt[g * 64 + b * 8 + j] = 0.f;
            Wgt[g * 64 + b * 8 + i0] = inv;
            Wgt[g * 64 + b * 8 + i1] = r * inv;
            needed[i0 * 8 + b] = 1;
            needed[i1 * 8 + b] = 1;
        }
        if (t < 8) {
            float v = 0.f;
            for (int bb = 0; bb < 8; ++bb) v += probs[bb * 8 + t];
            vsum[t] = v;
        }
        __syncthreads();
        if (t == 0) {
            float mean = 0.f;
            for (int j = 0; j < 8; ++j) mean += vsum[j];
            mean *= 0.125f;
            float var = 0.f;
            for (int j = 0; j < 8; ++j) { float d = vsum[j] - mean; var += d * d; }
            var *= (1.f / 7.f);
            losses[g] = var / (mean * mean + 1e-10f);
        }
        __syncthreads();
    }
    if (t == 0) loss_out[0] = 0.25f * (losses[0] + losses[1] + losses[2] + losses[3]);
}

// ---------------------------------------------------------------- pre: x -> bf16 swizzled
__global__ void pre_x(const float* __restrict__ x, u16* __restrict__ Xt) {
    int h = blockIdx.x, b = blockIdx.y, t = threadIdx.x;
    __shared__ u16 lds[12288];
    const float* xb = x + ((size_t)b * 128) * CHW + h * 96;
    for (int i = t; i < 12288; i += 256) {
        int c = i / 96, w = i - c * 96;
        lds[(c >> 6) * 6144 + w * 64 + ((c & 63) ^ ((w & 7) << 3))] = f2bf(xb[(size_t)c * CHW + w]);
    }
    __syncthreads();
    const unsigned* l32 = (const unsigned*)lds;
    unsigned* o32 = (unsigned*)Xt;
    for (int i = t; i < 6144; i += 256) {
        int hf = (i >= 3072) ? 1 : 0;
        int rem = i - hf * 3072;
        o32[((size_t)(b * 2 + hf) * 96 + h) * 3072 + rem] = l32[i];
    }
}

// ---------------------------------------------------------------- pre: Wc -> A_t
__global__ void pre_wc(const float* __restrict__ Wc, u16* __restrict__ At) {
    int eo = blockIdx.x;                 // e*128 + o
    int e = eo >> 7, o = eo & 127, t = threadIdx.x;
    __shared__ u16 lds[1152];
    const float* src = Wc + (size_t)eo * 1152;   // [c][r] flat: c*9+r
    for (int i = t; i < 1152; i += 128) lds[i] = f2bf(src[i]);
    __syncthreads();
    for (int i = t; i < 1152; i += 128) {
        int r = i >> 7, c = i & 127;
        At[((((size_t)(e * 2 + (c >> 6)) * 9 + r) * 128 + o) << 6) + (c & 63)] = lds[c * 9 + r];
    }
}

// ---------------------------------------------------------------- pre: Wp -> bf16
__global__ void pre_wp(const float* __restrict__ Wp, u16* __restrict__ Wpt) {
    int i = blockIdx.x * 256 + threadIdx.x;
    if (i < 131072) Wpt[i] = f2bf(Wp[i]);
}

// ---------------------------------------------------------------- fused expert (MFMA)
// Block: (e, b, 2 output rows h0,h0+1). 4 waves as 2M x 2N: wave tile = 64 oc x 96 px.
// Conv = 9 shifted GEMMs (K=128 in 2 c-halves), B-frags from LDS halo, A-frags from global.
__launch_bounds__(256, 2)
__global__ void expert_kernel(const u16* __restrict__ Xt, const u16* __restrict__ At,
                              const u16* __restrict__ Wpt,
                              const float* __restrict__ bc, const float* __restrict__ bp,
                              const float* __restrict__ ws, float* __restrict__ out) {
    int hs = blockIdx.x, b = blockIdx.y, e = blockIdx.z;
    const int* needed = (const int*)(ws + 1280);
    if (!needed[e * 8 + b]) return;
    int h0 = hs * 2;
    int t = threadIdx.x, lane = t & 63, wv = t >> 6;
    int mi = wv & 1, ni = wv >> 1;            // M-half, N-half(row)
    int lane15 = lane & 15, quad = lane >> 4, q8 = quad * 8;

    // LDS union: conv: Hs[4][98][64] bf16 (50176 B) | epi: part_s[192][8] f32 (6144) + v_s[192][128] bf16 (49152)
    __shared__ __align__(16) char smem[55296];
    u16* Hs = (u16*)smem;                  // row stride 6272 u16 = 12544 B
    float* part_s = (float*)smem;
    u16* v_s = (u16*)(smem + 6144);

    float gw[4];
    #pragma unroll
    for (int g = 0; g < 4; ++g) gw[g] = ws[1024 + g * 64 + b * 8 + e];

    f32x4 zero = {0.f, 0.f, 0.f, 0.f};
    f32x4 acc[24];                          // [mb][j] = mb*6 + j
    #pragma unroll
    for (int i = 0; i < 24; ++i) acc[i] = zero;

    int aoff[4];
    #pragma unroll
    for (int mb = 0; mb < 4; ++mb) aoff[mb] = (mi * 64 + mb * 16 + lane15) * 64 + q8;

    for (int hf = 0; hf < 2; ++hf) {
        __syncthreads();                    // Hs overwrite safe
        // ---- stage halo rows h0-1 .. h0+2 (cols 1..96 = data, 0/97 = zero)
        const u16* Xb = Xt + (size_t)(b * 2 + hf) * 96 * 6144;
        for (int rr = 0; rr < 4; ++rr) {
            int row = h0 - 1 + rr;
            u16* dst = Hs + rr * 6272;
            if (row >= 0 && row < 96) {
                const u16* src = Xb + (size_t)row * 6144;
                for (int i = t; i < 768; i += 256)
                    *(uint4*)(dst + 64 + i * 8) = *(const uint4*)(src + i * 8);
            } else {
                uint4 z; z.x = z.y = z.z = z.w = 0u;
                for (int i = t; i < 784; i += 256) *(uint4*)(dst + i * 8) = z;
            }
        }
        if (t < 64) {                       // border cols
            uint4 z; z.x = z.y = z.z = z.w = 0u;
            int rr = t >> 4, cs = (t >> 3) & 1, p = t & 7;
            *(uint4*)(Hs + rr * 6272 + cs * 97 * 64 + p * 8) = z;
        }
        __syncthreads();

        const u16* Ab = At + (size_t)(e * 2 + hf) * 9 * 8192;
        short8 afc[4];
        #pragma unroll
        for (int mb = 0; mb < 4; ++mb) afc[mb] = *(const short8*)(Ab + aoff[mb]);

        for (int r = 0; r < 9; ++r) {
            int dyi = (r * 11) >> 5;        // r/3
            int dxi = r - dyi * 3;          // dx+1
            int hb = (ni + dyi) * 12544;    // halo row byte offset
            int ba[6];
            #pragma unroll
            for (int j = 0; j < 6; ++j) {
                int col = j * 16 + lane15 + dxi;
                ba[j] = hb + col * 128 + ((q8 ^ (((col - 1) & 7) << 3)) << 1);
            }
            #pragma unroll
            for (int ck = 0; ck < 2; ++ck) {
                int chn = r * 2 + ck + 1;   // prefetch next A chunk
                if (chn > 17) chn = 17;
                short8 afn[4];
                #pragma unroll
                for (int mb = 0; mb < 4; ++mb)
                    afn[mb] = *(const short8*)(Ab + (chn >> 1) * 8192 + (chn & 1) * 32 + aoff[mb]);
                short8 bv[6];
                #pragma unroll
                for (int j = 0; j < 6; ++j)
                    bv[j] = *(const short8*)(smem + (ba[j] ^ (ck << 6)));
                #pragma unroll
                for (int mb = 0; mb < 4; ++mb)
                    #pragma unroll
                    for (int j = 0; j < 6; ++j)
                        acc[mb * 6 + j] = __builtin_amdgcn_mfma_f32_16x16x32_bf16(
                            afc[mb], bv[j], acc[mb * 6 + j], 0, 0, 0);
                #pragma unroll
                for (int mb = 0; mb < 4; ++mb) afc[mb] = afn[mb];
            }
        }
    }

    // ---- epilogue: bias + relu + squash -> v_s (bf16, swizzled)
    __syncthreads();                        // all conv LDS reads done
    int ob = e * 128 + mi * 64 + quad * 4;
    float bcv[16];
    #pragma unroll
    for (int mb = 0; mb < 4; ++mb)
        #pragma unroll
        for (int rg = 0; rg < 4; ++rg) bcv[mb * 4 + rg] = bc[ob + mb * 16 + rg];
    #pragma unroll
    for (int j = 0; j < 6; ++j) {
        float s = 0.f;
        #pragma unroll
        for (int mb = 0; mb < 4; ++mb) {
            f32x4 a = acc[mb * 6 + j];
            #pragma unroll
            for (int rg = 0; rg < 4; ++rg) {
                float u = fmaxf(a[rg] + bcv[mb * 4 + rg], 0.f);
                a[rg] = u; s += u * u;
            }
            acc[mb * 6 + j] = a;
        }
        part_s[(ni * 96 + j * 16 + lane15) * 8 + mi * 4 + quad] = s;
    }
    __syncthreads();
    float fs[6];
    #pragma unroll
    for (int j = 0; j < 6; ++j) {
        int n = ni * 96 + j * 16 + lane15;
        f32x4 p0 = *(const f32x4*)(part_s + n * 8);
        f32x4 p1 = *(const f32x4*)(part_s + n * 8 + 4);
        float sn = p0[0] + p0[1] + p0[2] + p0[3] + p1[0] + p1[1] + p1[2] + p1[3];
        fs[j] = sn / ((1.f + sn) * sqrtf(sn + 1e-8f));
    }
    #pragma unroll
    for (int j = 0; j < 6; ++j) {
        int n = ni * 96 + j * 16 + lane15;
        int sw = (n & 7) << 3;
        #pragma unroll
        for (int mb = 0; mb < 4; ++mb) {
            f32x4 a = acc[mb * 6 + j];
            short4 pk;
            pk.x = (short)f2bf(a[0] * fs[j]); pk.y = (short)f2bf(a[1] * fs[j]);
            pk.z = (short)f2bf(a[2] * fs[j]); pk.w = (short)f2bf(a[3] * fs[j]);
            int cb = mb * 16 + quad * 4;
            *(short4*)(v_s + n * 128 + ((cb ^ sw) | (mi * 64))) = pk;
        }
    }
    __syncthreads();

    // ---- pointwise GEMM: y = Wp . v
    #pragma unroll
    for (int i = 0; i < 24; ++i) acc[i] = zero;
    int voff[6];
    #pragma unroll
    for (int j = 0; j < 6; ++j) {
        int n = ni * 96 + j * 16 + lane15;
        voff[j] = 6144 + (n * 128 + (q8 ^ ((n & 7) << 3))) * 2;   // smem byte offset
    }
    const u16* We = Wpt + (size_t)e * 16384;
    #pragma unroll
    for (int hf = 0; hf < 2; ++hf)
        #pragma unroll
        for (int ck = 0; ck < 2; ++ck) {
            short8 af[4];
            #pragma unroll
            for (int mb = 0; mb < 4; ++mb)
                af[mb] = *(const short8*)(We + (mi * 64 + mb * 16 + lane15) * 128 + hf * 64 + ck * 32 + q8);
            short8 bv[6];
            #pragma unroll
            for (int j = 0; j < 6; ++j)
                bv[j] = *(const short8*)(smem + ((voff[j] ^ (ck << 6)) + hf * 128));
            #pragma unroll
            for (int mb = 0; mb < 4; ++mb)
                #pragma unroll
                for (int j = 0; j < 6; ++j)
                    acc[mb * 6 + j] = __builtin_amdgcn_mfma_f32_16x16x32_bf16(
                        af[mb], bv[j], acc[mb * 6 + j], 0, 0, 0);
        }

    // ---- bias + gate-weighted scatter
    int row = h0 + ni;
    #pragma unroll
    for (int mb = 0; mb < 4; ++mb) {
        #pragma unroll
        for (int rg = 0; rg < 4; ++rg) {
            int o = mi * 64 + mb * 16 + quad * 4 + rg;
            float bias = bp[e * 128 + o];
            size_t obase = ((size_t)(b * 128 + o)) * CHW + row * 96 + lane15;
            #pragma unroll
            for (int j = 0; j < 6; ++j) {
                float y = acc[mb * 6 + j][rg] + bias;
                #pragma unroll
                for (int g = 0; g < 4; ++g)
                    if (gw[g] != 0.f)
                        atomicAdd(out + (size_t)g * OPG + obase + j * 16, gw[g] * y);
            }
        }
    }
}

// ---------------------------------------------------------------- launch
extern "C" void kernel_launch(void* const* d_in, const int* in_sizes, int n_in,
                              void* d_out, int out_size, void* d_ws, size_t ws_size,
                              hipStream_t stream) {
    const float* x  = (const float*)d_in[0];
    const float* G  = (const float*)d_in[1];
    const float* Wc = (const float*)d_in[2];
    const float* bc = (const float*)d_in[3];
    const float* Wp = (const float*)d_in[4];
    const float* bp = (const float*)d_in[5];
    float* out = (float*)d_out;
    float* ws  = (float*)d_ws;
    u16* Xt  = (u16*)((char*)d_ws + WS_XT);
    u16* At  = (u16*)((char*)d_ws + WS_AT);
    u16* Wpt = (u16*)((char*)d_ws + WS_WPT);

    hipMemsetAsync(d_out, 0, (size_t)out_size * sizeof(float), stream);
    gap_kernel<<<dim3(1024), dim3(256), 0, stream>>>(x, ws);
    gate_kernel<<<dim3(1), dim3(64), 0, stream>>>(G, ws, out + (size_t)4 * OPG);
    pre_x<<<dim3(96, 8), dim3(256), 0, stream>>>(x, Xt);
    pre_wc<<<dim3(1024), dim3(128), 0, stream>>>(Wc, At);
    pre_wp<<<dim3(512), dim3(256), 0, stream>>>(Wp, Wpt);
    expert_kernel<<<dim3(48, 8, 8), dim3(256), 0, stream>>>(Xt, At, Wpt, bc, bp, ws, out);
}

// Round 5
// 443.694 us; speedup vs baseline: 12.0751x; 1.3625x over previous
//
#include <hip/hip_runtime.h>
#include <math.h>

// E=8, TOP=2, C=128, H=96, W=96, B=8, NUM_GATES=4, KH=3
#define CHW 9216
#define OPG 9437184  // 8*128*96*96

typedef unsigned short u16;
typedef __attribute__((ext_vector_type(8))) short short8;   // 8 x bf16 (4 VGPR)
typedef __attribute__((ext_vector_type(4))) float f32x4;

// ws layout (bytes):
// [0, 8192)            gating (floats): x_gap[1024]; idx2[4][8][2] int @1344f; wt2[4][8][2] @1408f
// [8192, 18882560)     X_t  bf16 [b][hf][h][w][c64]  (c swizzled: c^((w&7)<<3))
// [18882560, 21241856) A_t2 bf16 [e][hf][r][ck][mi][mb][lane][8]  (wave-fragment order)
// [21241856, 21504000) Wp_t bf16 [e][o][c128]
#define WS_XT  8192
#define WS_AT  18882560
#define WS_WPT 21241856

__device__ __forceinline__ u16 f2bf(float f) {
    unsigned u = __float_as_uint(f);
    u += 0x7fff + ((u >> 16) & 1);      // RNE
    return (u16)(u >> 16);
}

// ---------------------------------------------------------------- x_gap
__global__ void gap_kernel(const float* __restrict__ x, float* __restrict__ xgap) {
    int bc = blockIdx.x;
    const float* p = x + (size_t)bc * CHW;
    float s = 0.f;
    for (int i = threadIdx.x; i < CHW; i += 256) s += p[i];
    __shared__ float red[256];
    red[threadIdx.x] = s;
    __syncthreads();
    for (int off = 128; off > 0; off >>= 1) {
        if (threadIdx.x < off) red[threadIdx.x] += red[threadIdx.x + off];
        __syncthreads();
    }
    if (threadIdx.x == 0) xgap[bc] = red[0] * (1.0f / 9216.0f);
}

// ---------------------------------------------------------------- gating (exact fp32)
__global__ void gate_kernel(const float* __restrict__ G, float* __restrict__ ws,
                            float* __restrict__ loss_out) {
    __shared__ float gap_s[1024];
    __shared__ float logits[64];
    __shared__ float probs[64];
    __shared__ float vsum[8];
    __shared__ float losses[4];
    int t = threadIdx.x;
    for (int i = t; i < 1024; i += 64) gap_s[i] = ws[i];
    int b = t >> 3, e = t & 7;
    int* iw = (int*)(ws + 1344);
    float* wt = ws + 1408;
    __syncthreads();
    for (int g = 0; g < 4; ++g) {
        float acc = 0.f;
        const float* Gg = G + g * 1024;
        for (int c = 0; c < 128; ++c) acc += gap_s[b * 128 + c] * Gg[c * 8 + e];
        logits[t] = acc;
        __syncthreads();
        float m = -1e30f;
        for (int j = 0; j < 8; ++j) m = fmaxf(m, logits[b * 8 + j]);
        float den = 0.f;
        for (int j = 0; j < 8; ++j) den += expf(logits[b * 8 + j] - m);
        float pr = expf(acc - m) / den;
        probs[t] = pr;
        __syncthreads();
        if (e == 0) {
            int i0 = 0; float v0 = probs[b * 8];
            for (int j = 1; j < 8; ++j) { float v = probs[b * 8 + j]; if (v > v0) { v0 = v; i0 = j; } }
            int i1 = -1; float v1 = -1e30f;
            for (int j = 0; j < 8; ++j) { if (j == i0) continue; float v = probs[b * 8 + j]; if (v > v1) { v1 = v; i1 = j; } }
            float r = expf(v1 - v0);              // softmax over [v0,v1]
            float inv = 1.f / (1.f + r);
            iw[g * 16 + b * 2 + 0] = i0;
            iw[g * 16 + b * 2 + 1] = i1;
            wt[g * 16 + b * 2 + 0] = inv;
            wt[g * 16 + b * 2 + 1] = r * inv;
        }
        if (t < 8) {
            float v = 0.f;
            for (int bb = 0; bb < 8; ++bb) v += probs[bb * 8 + t];
            vsum[t] = v;
        }
        __syncthreads();
        if (t == 0) {
            float mean = 0.f;
            for (int j = 0; j < 8; ++j) mean += vsum[j];
            mean *= 0.125f;
            float var = 0.f;
            for (int j = 0; j < 8; ++j) { float d = vsum[j] - mean; var += d * d; }
            var *= (1.f / 7.f);
            losses[g] = var / (mean * mean + 1e-10f);
        }
        __syncthreads();
    }
    if (t == 0) loss_out[0] = 0.25f * (losses[0] + losses[1] + losses[2] + losses[3]);
}

// ---------------------------------------------------------------- pre: x -> bf16 swizzled
__global__ void pre_x(const float* __restrict__ x, u16* __restrict__ Xt) {
    int h = blockIdx.x, b = blockIdx.y, t = threadIdx.x;
    __shared__ u16 lds[12288];
    const float* xb = x + ((size_t)b * 128) * CHW + h * 96;
    for (int i = t; i < 12288; i += 256) {
        int c = i / 96, w = i - c * 96;
        lds[(c >> 6) * 6144 + w * 64 + ((c & 63) ^ ((w & 7) << 3))] = f2bf(xb[(size_t)c * CHW + w]);
    }
    __syncthreads();
    const unsigned* l32 = (const unsigned*)lds;
    unsigned* o32 = (unsigned*)Xt;
    for (int i = t; i < 6144; i += 256) {
        int hf = (i >= 3072) ? 1 : 0;
        int rem = i - hf * 3072;
        o32[((size_t)(b * 2 + hf) * 96 + h) * 3072 + rem] = l32[i];
    }
}

// ---------------------------------------------------------------- pre: Wc -> A_t2 (fragment order)
// At2 u16 index: (((((e*2+hf)*9+r)*2+ck)*2+mi)*4+mb)*512 + lane*8 + s
// value = Wc[e][o=mi*64+mb*16+(lane&15)][cin=hf*64+ck*32+(lane>>4)*8+s][tap r]
__global__ void pre_wc2(const float* __restrict__ Wc, u16* __restrict__ At2) {
    int idx = blockIdx.x * 256 + threadIdx.x;          // < 1179648
    int s = idx & 7;
    int lane = (idx >> 3) & 63;
    int mb = (idx >> 9) & 3;
    int mi = (idx >> 11) & 1;
    int ck = (idx >> 12) & 1;
    int rem = idx >> 13;                                // 0..143
    int r = rem % 9;
    int rem2 = rem / 9;                                 // 0..15
    int hf = rem2 & 1;
    int e = rem2 >> 1;
    int l15 = lane & 15, quad = lane >> 4;
    int o = mi * 64 + mb * 16 + l15;
    int cin = hf * 64 + ck * 32 + quad * 8 + s;
    size_t src = (((size_t)e * 128 + o) * 128 + cin) * 9 + r;
    At2[idx] = f2bf(Wc[src]);
}

// ---------------------------------------------------------------- pre: Wp -> bf16
__global__ void pre_wp(const float* __restrict__ Wp, u16* __restrict__ Wpt) {
    int i = blockIdx.x * 256 + threadIdx.x;
    if (i < 131072) Wpt[i] = f2bf(Wp[i]);
}

// ---------------------------------------------------------------- fused dual-expert gate block
// Block: (hs, b, g) -> 2 output rows, both top-2 experts, writes out[g] once (no atomics).
// 512 threads = 8 waves: mi = M-half (64 ch), ni = quarter of 192 px (48 px, j=3 tiles).
// Conv: 9 shifted GEMMs, B-frags (pixels) shared across both experts; A-frags coalesced from L2.
__launch_bounds__(512, 2)
__global__ void expert_kernel(const u16* __restrict__ Xt, const u16* __restrict__ At2,
                              const u16* __restrict__ Wpt,
                              const float* __restrict__ bc, const float* __restrict__ bp,
                              const float* __restrict__ ws, float* __restrict__ out) {
    int hs = blockIdx.x, b = blockIdx.y, g = blockIdx.z;
    int h0 = hs * 2;
    int t = threadIdx.x, lane = t & 63, wv = t >> 6;
    int mi = wv & 1, ni = wv >> 1;                 // ni 0..3
    int l15 = lane & 15, quad = lane >> 4, q8 = quad * 8;
    int nrow = ni >> 1;                            // local output row 0/1
    int ncb = (ni & 1) * 48;                       // pixel-col base

    const int* iw = (const int*)(ws + 1344);
    const float* wt = ws + 1408;
    int ee[2];
    float wwt[2];
    ee[0] = iw[g * 16 + b * 2 + 0]; ee[1] = iw[g * 16 + b * 2 + 1];
    wwt[0] = wt[g * 16 + b * 2 + 0]; wwt[1] = wt[g * 16 + b * 2 + 1];

    // LDS union: conv Hs[4][98][64] bf16 (50176 B) | epi part_s[192][12] f32 (9216) + v_s[192][128] bf16 (49152)
    __shared__ __align__(16) char smem[58368];
    u16* Hs = (u16*)smem;                          // halo row stride 6272 u16 = 12544 B
    float* part_s = (float*)smem;
    u16* v_s = (u16*)(smem + 9216);

    f32x4 zero = {0.f, 0.f, 0.f, 0.f};
    f32x4 acc[2][12];                              // [expert][mb*3 + j]
    #pragma unroll
    for (int i = 0; i < 12; ++i) { acc[0][i] = zero; acc[1][i] = zero; }

    int abase = mi * 2048 + lane * 8;              // u16 offset within (e,hf,step)

    // ======== conv: both experts share staged halo + B-frags ========
    for (int hf = 0; hf < 2; ++hf) {
        __syncthreads();
        const u16* Xb = Xt + (size_t)(b * 2 + hf) * 96 * 6144;
        for (int rr = 0; rr < 4; ++rr) {
            int row = h0 - 1 + rr;
            u16* dst = Hs + rr * 6272;
            if (row >= 0 && row < 96) {
                const u16* src = Xb + (size_t)row * 6144;
                for (int i = t; i < 768; i += 512)
                    *(uint4*)(dst + 64 + i * 8) = *(const uint4*)(src + i * 8);
            } else {
                uint4 z; z.x = z.y = z.z = z.w = 0u;
                for (int i = t; i < 784; i += 512) *(uint4*)(dst + i * 8) = z;
            }
        }
        if (t < 64) {                              // border cols 0 / 97
            uint4 z; z.x = z.y = z.z = z.w = 0u;
            int rr = t >> 4, cs = (t >> 3) & 1, p = t & 7;
            *(uint4*)(Hs + rr * 6272 + cs * 97 * 64 + p * 8) = z;
        }
        __syncthreads();

        const u16* A0 = At2 + (size_t)(ee[0] * 2 + hf) * 73728;
        const u16* A1 = At2 + (size_t)(ee[1] * 2 + hf) * 73728;
        short8 c0[4], c1[4];
        #pragma unroll
        for (int mb = 0; mb < 4; ++mb) {
            c0[mb] = *(const short8*)(A0 + abase + mb * 512);
            c1[mb] = *(const short8*)(A1 + abase + mb * 512);
        }
        for (int s = 0; s < 18; ++s) {             // s = r*2 + ck
            int r = s >> 1, ck = s & 1;
            int dyi = (r * 11) >> 5;               // r/3
            int dxi = r - dyi * 3;
            int hb = (nrow + dyi) * 12544;
            int sn = (s < 17) ? s + 1 : 17;        // prefetch next step
            int noff = sn * 4096 + abase;
            short8 n0[4], n1[4];
            #pragma unroll
            for (int mb = 0; mb < 4; ++mb) {
                n0[mb] = *(const short8*)(A0 + noff + mb * 512);
                n1[mb] = *(const short8*)(A1 + noff + mb * 512);
            }
            short8 bv[3];
            #pragma unroll
            for (int j = 0; j < 3; ++j) {
                int col = ncb + j * 16 + l15 + dxi;
                int ba = hb + col * 128 + ((q8 ^ (((col - 1) & 7) << 3)) << 1);
                bv[j] = *(const short8*)(smem + (ba ^ (ck << 6)));
            }
            #pragma unroll
            for (int mb = 0; mb < 4; ++mb)
                #pragma unroll
                for (int j = 0; j < 3; ++j) {
                    acc[0][mb * 3 + j] = __builtin_amdgcn_mfma_f32_16x16x32_bf16(c0[mb], bv[j], acc[0][mb * 3 + j], 0, 0, 0);
                    acc[1][mb * 3 + j] = __builtin_amdgcn_mfma_f32_16x16x32_bf16(c1[mb], bv[j], acc[1][mb * 3 + j], 0, 0, 0);
                }
            #pragma unroll
            for (int mb = 0; mb < 4; ++mb) { c0[mb] = n0[mb]; c1[mb] = n1[mb]; }
        }
    }

    // ======== epilogue per expert: bias+relu+squash -> v_s -> pointwise ========
    #pragma unroll
    for (int xp = 0; xp < 2; ++xp) {
        int e_ = ee[xp];
        __syncthreads();   // xp=0: conv LDS reads done; xp=1: pw0's v_s reads done
        #pragma unroll
        for (int j = 0; j < 3; ++j) {
            int n = ni * 48 + j * 16 + l15;
            float ssum = 0.f;
            #pragma unroll
            for (int mb = 0; mb < 4; ++mb) {
                f32x4 a = acc[xp][mb * 3 + j];
                #pragma unroll
                for (int rg = 0; rg < 4; ++rg) {
                    float u = fmaxf(a[rg] + bc[e_ * 128 + mi * 64 + mb * 16 + quad * 4 + rg], 0.f);
                    a[rg] = u; ssum += u * u;
                }
                acc[xp][mb * 3 + j] = a;
            }
            part_s[n * 12 + mi * 4 + quad] = ssum;
        }
        __syncthreads();
        #pragma unroll
        for (int j = 0; j < 3; ++j) {
            int n = ni * 48 + j * 16 + l15;
            f32x4 p0 = *(const f32x4*)(part_s + n * 12);
            f32x4 p1 = *(const f32x4*)(part_s + n * 12 + 4);
            float sn2 = p0[0] + p0[1] + p0[2] + p0[3] + p1[0] + p1[1] + p1[2] + p1[3];
            float fsj = sn2 / ((1.f + sn2) * sqrtf(sn2 + 1e-8f));
            int sw = (n & 7) << 3;
            #pragma unroll
            for (int mb = 0; mb < 4; ++mb) {
                f32x4 a = acc[xp][mb * 3 + j];
                short4 pk;
                pk.x = (short)f2bf(a[0] * fsj); pk.y = (short)f2bf(a[1] * fsj);
                pk.z = (short)f2bf(a[2] * fsj); pk.w = (short)f2bf(a[3] * fsj);
                int cb = mb * 16 + quad * 4;
                *(short4*)(v_s + n * 128 + ((cb ^ sw) | (mi << 6))) = pk;
            }
        }
        __syncthreads();
        #pragma unroll
        for (int i = 0; i < 12; ++i) acc[xp][i] = zero;
        const u16* We_ = Wpt + (size_t)e_ * 16384;
        #pragma unroll
        for (int kk = 0; kk < 4; ++kk) {
            short8 af[4];
            #pragma unroll
            for (int mb = 0; mb < 4; ++mb)
                af[mb] = *(const short8*)(We_ + (mi * 64 + mb * 16 + l15) * 128 + kk * 32 + q8);
            short8 bvv[3];
            #pragma unroll
            for (int j = 0; j < 3; ++j) {
                int n = ni * 48 + j * 16 + l15;
                int sw = (n & 7) << 3;
                int pos = ((kk & 2) << 5) | ((((kk & 1) << 5) + q8) ^ sw);
                bvv[j] = *(const short8*)(v_s + n * 128 + pos);
            }
            #pragma unroll
            for (int mb = 0; mb < 4; ++mb)
                #pragma unroll
                for (int j = 0; j < 3; ++j)
                    acc[xp][mb * 3 + j] = __builtin_amdgcn_mfma_f32_16x16x32_bf16(af[mb], bvv[j], acc[xp][mb * 3 + j], 0, 0, 0);
        }
    }

    // ======== mix + store (exactly once, coalesced) ========
    int row = h0 + nrow;
    #pragma unroll
    for (int mb = 0; mb < 4; ++mb)
        #pragma unroll
        for (int rg = 0; rg < 4; ++rg) {
            int o = mi * 64 + mb * 16 + quad * 4 + rg;
            float y0b = bp[ee[0] * 128 + o];
            float y1b = bp[ee[1] * 128 + o];
            size_t obase = (size_t)g * OPG + ((size_t)(b * 128 + o)) * CHW + (size_t)row * 96;
            #pragma unroll
            for (int j = 0; j < 3; ++j) {
                float y0 = acc[0][mb * 3 + j][rg] + y0b;
                float y1 = acc[1][mb * 3 + j][rg] + y1b;
                out[obase + ncb + j * 16 + l15] = wwt[0] * y0 + wwt[1] * y1;
            }
        }
}

// ---------------------------------------------------------------- launch
extern "C" void kernel_launch(void* const* d_in, const int* in_sizes, int n_in,
                              void* d_out, int out_size, void* d_ws, size_t ws_size,
                              hipStream_t stream) {
    const float* x  = (const float*)d_in[0];
    const float* G  = (const float*)d_in[1];
    const float* Wc = (const float*)d_in[2];
    const float* bc = (const float*)d_in[3];
    const float* Wp = (const float*)d_in[4];
    const float* bp = (const float*)d_in[5];
    float* out = (float*)d_out;
    float* ws  = (float*)d_ws;
    u16* Xt  = (u16*)((char*)d_ws + WS_XT);
    u16* At2 = (u16*)((char*)d_ws + WS_AT);
    u16* Wpt = (u16*)((char*)d_ws + WS_WPT);

    gap_kernel<<<dim3(1024), dim3(256), 0, stream>>>(x, ws);
    gate_kernel<<<dim3(1), dim3(64), 0, stream>>>(G, ws, out + (size_t)4 * OPG);
    pre_x<<<dim3(96, 8), dim3(256), 0, stream>>>(x, Xt);
    pre_wc2<<<dim3(4608), dim3(256), 0, stream>>>(Wc, At2);
    pre_wp<<<dim3(512), dim3(256), 0, stream>>>(Wp, Wpt);
    expert_kernel<<<dim3(48, 8, 4), dim3(512), 0, stream>>>(Xt, At2, Wpt, bc, bp, ws, out);
}